// Round 15
// baseline (462.284 us; speedup 1.0000x reference)
//
#include <hip/hip_runtime.h>

#define NI 32
#define CI 128
#define HI 112
#define WI 112
#define OC 256
#define HO 110
#define WO 110

typedef float f32x4 __attribute__((ext_vector_type(4)));
typedef short s16x8 __attribute__((ext_vector_type(8)));

typedef const unsigned int __attribute__((address_space(1))) gu32;
typedef unsigned int __attribute__((address_space(3))) lu32;

__device__ __forceinline__ ushort f2bf(float f) {
  union { float f; unsigned int u; } x; x.f = f;
  unsigned int r = x.u + 0x7FFFu + ((x.u >> 16) & 1u);
  return (ushort)(r >> 16);
}

// weight [oc][c][kh][kw] fp32 -> wp [kk][cq][oc][32ch] bf16  (cq = 32-ch quarter)
__global__ __launch_bounds__(256) void pack_w_kernel(const float* __restrict__ w,
                                                     ushort* __restrict__ wp) {
  int i = blockIdx.x * 256 + threadIdx.x;  // 294912
  int e = i & 7;
  int k8 = (i >> 3) & 3;
  int oc = (i >> 5) & 255;
  int cq = (i >> 13) & 3;
  int kk = i >> 15;  // 0..8
  int ch = cq * 32 + k8 * 8 + e;
  int kh = kk / 3, kw = kk - kh * 3;
  wp[i] = f2bf(w[((oc * CI + ch) * 3 + kh) * 3 + kw]);
}

// x [n][c][h][w] fp32 -> xn [n][cq][h][w][32c] bf16.
// Coalesced reads (lane<->w), 16B-chunk XOR-swizzled LDS transpose, uint4 writes.
__global__ __launch_bounds__(256) void to_nhwc_kernel(const float* __restrict__ x,
                                                      ushort* __restrict__ xn) {
  __shared__ ushort lds[1792 * 8];  // 1792 16B chunks (112 w x 16 chunks), 28 KB
  int b = blockIdx.x;               // n*112 + h
  int n = b / HI;
  int h = b - n * HI;
  const float* xr = x + ((size_t)n * CI * HI) * WI + (size_t)h * WI;
  int t = threadIdx.x;
  int w = t & 127;   // active if < 112
  int cph = t >> 7;  // 0..1
  if (w < WI) {
    #pragma unroll
    for (int it = 0; it < 32; ++it) {
      int cp = it * 2 + cph;  // channel pair 0..63
      int c = cp * 2;
      float f0 = xr[(size_t)c * (HI * WI) + w];
      float f1 = xr[(size_t)(c + 1) * (HI * WI) + w];
      unsigned int pk = (unsigned int)f2bf(f0) | ((unsigned int)f2bf(f1) << 16);
      int chunk = w * 16 + ((cp >> 2) ^ (w & 15));
      *(unsigned int*)((char*)lds + chunk * 16 + (cp & 3) * 4) = pk;
    }
  }
  __syncthreads();
  #pragma unroll
  for (int it = 0; it < 7; ++it) {
    int j = it * 256 + t;  // chunk id: w = j>>4, c8 = j&15
    int w2 = j >> 4, c8 = j & 15;
    int src = w2 * 16 + (c8 ^ (w2 & 15));
    uint4 v = *(const uint4*)((const char*)lds + src * 16);
    int cq = c8 >> 2, g = c8 & 3;
    *(uint4*)&xn[((((size_t)n * 4 + cq) * HI + h) * WI + w2) * 32 + g * 8] = v;
  }
}

// Implicit GEMM, 16x16x32 MFMA. BLOCK-level pixel split (branch-free):
// 2 blocks per (n,oh): ph0 computes pix 0..63, ph1 pix 46..109 — both
// exactly nf=4 (16% overlap recompute; stores predicated in epilogue only).
// Block = 256 thr = 4 waves x 64 oc. Each block stages only its 66-px
// window: 12.7 KB/quarter, double-buffered 25.3 KB -> 4 blocks/CU =
// 4 waves/SIMD. acc[4][4]=64 AGPR + abuf[2][4]=32 VGPR + per-nf b fits
// the 128-reg cap of __launch_bounds__(256,4) (R9-style budget).
#define LROW 66  // window pixels (64 + 2 halo for kw)
__global__ __launch_bounds__(256, 4) void conv_mfma_kernel(const ushort* __restrict__ xn,
                                                           const ushort* __restrict__ wp,
                                                           const float* __restrict__ bias,
                                                           float* __restrict__ out) {
  __shared__ ushort lds[2 * 3 * LROW * 32];  // 2 quarter buffers, 12672 B each
  const int bid = blockIdx.x;
  // bijective XCD swizzle (7040 = 8*880); the ph pair of one (n,oh) adjacent
  const int orig = (bid & 7) * 880 + (bid >> 3);
  const int p = orig >> 1;
  const int ph = orig & 1;  // pixel-half: 0 -> ow 0..63, 1 -> ow 46..109
  const int n = p / HO;
  const int oh = p - n * HO;
  const int pb = ph * 46;  // window base pixel
  const int t = threadIdx.x;
  const int lane = t & 63;
  const int wid = t >> 6;  // 0..3: oc 64-block
  const int lane15 = lane & 15;
  const int laneh = lane >> 4;  // 0..3
  const int oc0 = wid * 64;
  char* ldsb = (char*)lds;

  f32x4 acc[4][4] = {};  // [mf: oc 16-frag][nf: pix 16-frag] — 64 AGPR
  s16x8 abuf[2][4];      // A parity ring (32 VGPR)

#define A_PRE(gg)                                                                        \
  {                                                                                      \
    const int q_ = (gg) / 9, kk_ = (gg) - q_ * 9;                                        \
    const ushort* wb_ = wp + ((size_t)(kk_ * 4 + q_)) * 8192 + (oc0 + lane15) * 32 +     \
                        laneh * 8;                                                       \
    _Pragma("unroll") for (int mf = 0; mf < 4; ++mf)                                     \
        abuf[(gg) & 1][mf] = *(const s16x8*)(wb_ + mf * 512);                            \
  }

// stage quarter qq: 3 input rows (oh..oh+2) x window [pb..pb+65] x 32 ch.
// Linear LDS dest; source pre-swizzled so reads at cs^((lp>>1)&3) are linear.
#define STAGE(qq)                                                                        \
  {                                                                                      \
    char* ldst_ = ldsb + (((qq) & 1) * (3 * LROW * 64));                                 \
    const ushort* gq_ = xn + (((size_t)n * 4 + (qq)) * HI + oh) * (WI * 32);             \
    _Pragma("unroll") for (int i = 0; i < 4; ++i) {                                      \
      int idx = i * 256 + t;                                                             \
      if (idx < 3 * LROW * 4) {                                                          \
        int cs = idx & 3;                                                                \
        int pr = idx >> 2;  /* 0..197 = r*LROW+lp */                                     \
        int r_ = (pr >= 2 * LROW) ? 2 : (pr >= LROW ? 1 : 0);                            \
        int lp = pr - r_ * LROW;                                                         \
        int scs = cs ^ ((lp >> 1) & 3);                                                  \
        const ushort* gsrc_ = gq_ + ((size_t)r_ * WI + pb + lp) * 32 + scs * 8;          \
        __builtin_amdgcn_global_load_lds((gu32*)gsrc_, (lu32*)(ldst_ + idx * 16), 16,    \
                                         0, 0);                                          \
      }                                                                                  \
    }                                                                                    \
  }

  // ---- prologue: A(0) first (clean wait), then stage(0) ----
  A_PRE(0)
  STAGE(0)
  __syncthreads();

  #pragma unroll
  for (int q = 0; q < 4; ++q) {
    if (q) __syncthreads();  // prev readers done; stage(q) landed (issued 9 taps ago)
    if (q < 3) STAGE(q + 1)  // double-buffer: 1-quarter lead
    const int qb = (q & 1) * (3 * LROW * 64);
    #pragma unroll
    for (int kk = 0; kk < 9; ++kk) {
      const int g = q * 9 + kk;
      const int kh = kk / 3, kw = kk - kh * 3;
      if (g + 1 < 36) A_PRE(g + 1)  // distance-1 parity ring
      __builtin_amdgcn_s_setprio(1);
      #pragma unroll
      for (int nf = 0; nf < 4; ++nf) {  // branch-free: all waves nf=4
        int lp = nf * 16 + lane15 + kw;             // local window pixel
        int pr = kh * LROW + lp;                    // LDS pixel-row
        int addr = qb + (pr << 6) + ((laneh ^ ((lp >> 1) & 3)) << 4);
        s16x8 b = *(const s16x8*)(ldsb + addr);
        #pragma unroll
        for (int mf = 0; mf < 4; ++mf)
          acc[mf][nf] = __builtin_amdgcn_mfma_f32_16x16x32_bf16(abuf[g & 1][mf], b,
                                                                acc[mf][nf], 0, 0, 0);
      }
      __builtin_amdgcn_s_setprio(0);
    }
  }
#undef A_PRE
#undef STAGE

  // ---- epilogue: D col=lane15 -> pix, row=laneh*4+r -> oc.
  // ph0 stores ow 0..63; ph1 stores only ow >= 64 (overlap owned by ph0).
  float* outb = out + ((size_t)n * OC) * (HO * WO) + (size_t)oh * WO;
  #pragma unroll
  for (int mf = 0; mf < 4; ++mf) {
    #pragma unroll
    for (int r = 0; r < 4; ++r) {
      const int oc = oc0 + mf * 16 + laneh * 4 + r;
      const float bv = bias[oc];
      float* op = outb + (size_t)oc * (HO * WO);
      #pragma unroll
      for (int nf = 0; nf < 4; ++nf) {
        int ow = pb + nf * 16 + lane15;
        bool keep = ph ? (ow >= 64 && ow < WO) : true;
        if (keep) op[ow] = acc[mf][nf][r] + bv;
      }
    }
  }
}
#undef LROW

// Correctness fallback if ws is too small for the packed bf16 buffers.
__global__ __launch_bounds__(256) void conv_naive_kernel(const float* __restrict__ x,
                                                         const float* __restrict__ w,
                                                         const float* __restrict__ bias,
                                                         float* __restrict__ out) {
  long i = (long)blockIdx.x * 256 + threadIdx.x;
  const long total = (long)NI * OC * HO * WO;
  if (i >= total) return;
  int ow = (int)(i % WO);
  long r1 = i / WO;
  int oh = (int)(r1 % HO);
  long r2 = r1 / HO;
  int oc = (int)(r2 % OC);
  int n = (int)(r2 / OC);
  float s = bias[oc];
  const float* xb = x + ((size_t)n * CI * HI) * WI;
  const float* wb = w + (size_t)oc * CI * 9;
  for (int c = 0; c < CI; ++c)
    for (int kh = 0; kh < 3; ++kh)
      for (int kw = 0; kw < 3; ++kw)
        s += xb[((size_t)c * HI + oh + kh) * WI + ow + kw] * wb[(c * 3 + kh) * 3 + kw];
  out[i] = s;
}

extern "C" void kernel_launch(void* const* d_in, const int* in_sizes, int n_in,
                              void* d_out, int out_size, void* d_ws, size_t ws_size,
                              hipStream_t stream) {
  const float* x = (const float*)d_in[0];
  const float* w = (const float*)d_in[1];
  const float* bias = (const float*)d_in[2];
  float* out = (float*)d_out;

  const size_t xn_elems = (size_t)NI * 4 * HI * WI * 32;  // 51,380,224
  const size_t wp_elems = (size_t)9 * 4 * 256 * 32;       // 294,912
  const size_t need = (xn_elems + wp_elems) * sizeof(ushort);

  if (ws_size >= need) {
    ushort* xnw = (ushort*)d_ws;
    ushort* wpw = xnw + xn_elems;
    hipLaunchKernelGGL(pack_w_kernel, dim3((unsigned)(wp_elems / 256)), dim3(256), 0, stream,
                       w, wpw);
    hipLaunchKernelGGL(to_nhwc_kernel, dim3(NI * HI), dim3(256), 0, stream, x, xnw);
    hipLaunchKernelGGL(conv_mfma_kernel, dim3(NI * HO * 2), dim3(256), 0, stream, xnw, wpw,
                       bias, out);
  } else {
    long total = (long)NI * OC * HO * WO;
    hipLaunchKernelGGL(conv_naive_kernel, dim3((unsigned)((total + 255) / 256)), dim3(256), 0,
                       stream, x, w, bias, out);
  }
}

// Round 16
// 307.463 us; speedup vs baseline: 1.5035x; 1.5035x over previous
//
#include <hip/hip_runtime.h>

#define NI 32
#define CI 128
#define HI 112
#define WI 112
#define OC 256
#define HO 110
#define WO 110

typedef float f32x4 __attribute__((ext_vector_type(4)));
typedef short s16x8 __attribute__((ext_vector_type(8)));

typedef const unsigned int __attribute__((address_space(1))) gu32;
typedef unsigned int __attribute__((address_space(3))) lu32;

__device__ __forceinline__ ushort f2bf(float f) {
  union { float f; unsigned int u; } x; x.f = f;
  unsigned int r = x.u + 0x7FFFu + ((x.u >> 16) & 1u);
  return (ushort)(r >> 16);
}

// weight [oc][c][kh][kw] fp32 -> wp [kk][cq][oc][32ch] bf16  (cq = 32-ch quarter)
__global__ __launch_bounds__(256) void pack_w_kernel(const float* __restrict__ w,
                                                     ushort* __restrict__ wp) {
  int i = blockIdx.x * 256 + threadIdx.x;  // 294912
  int e = i & 7;
  int k8 = (i >> 3) & 3;
  int oc = (i >> 5) & 255;
  int cq = (i >> 13) & 3;
  int kk = i >> 15;  // 0..8
  int ch = cq * 32 + k8 * 8 + e;
  int kh = kk / 3, kw = kk - kh * 3;
  wp[i] = f2bf(w[((oc * CI + ch) * 3 + kh) * 3 + kw]);
}

// x [n][c][h][w] fp32 -> xn [n][cq][h][w][32c] bf16.
// Coalesced reads (lane<->w), 16B-chunk XOR-swizzled LDS transpose, uint4 writes.
__global__ __launch_bounds__(256) void to_nhwc_kernel(const float* __restrict__ x,
                                                      ushort* __restrict__ xn) {
  __shared__ ushort lds[1792 * 8];  // 1792 16B chunks (112 w x 16 chunks), 28 KB
  int b = blockIdx.x;               // n*112 + h
  int n = b / HI;
  int h = b - n * HI;
  const float* xr = x + ((size_t)n * CI * HI) * WI + (size_t)h * WI;
  int t = threadIdx.x;
  int w = t & 127;   // active if < 112
  int cph = t >> 7;  // 0..1
  if (w < WI) {
    #pragma unroll
    for (int it = 0; it < 32; ++it) {
      int cp = it * 2 + cph;  // channel pair 0..63
      int c = cp * 2;
      float f0 = xr[(size_t)c * (HI * WI) + w];
      float f1 = xr[(size_t)(c + 1) * (HI * WI) + w];
      unsigned int pk = (unsigned int)f2bf(f0) | ((unsigned int)f2bf(f1) << 16);
      int chunk = w * 16 + ((cp >> 2) ^ (w & 15));
      *(unsigned int*)((char*)lds + chunk * 16 + (cp & 3) * 4) = pk;
    }
  }
  __syncthreads();
  #pragma unroll
  for (int it = 0; it < 7; ++it) {
    int j = it * 256 + t;  // chunk id: w = j>>4, c8 = j&15
    int w2 = j >> 4, c8 = j & 15;
    int src = w2 * 16 + (c8 ^ (w2 & 15));
    uint4 v = *(const uint4*)((const char*)lds + src * 16);
    int cq = c8 >> 2, g = c8 & 3;
    *(uint4*)&xn[((((size_t)n * 4 + cq) * HI + h) * WI + w2) * 32 + g * 8] = v;
  }
}

// Implicit GEMM, 16x16x32 MFMA. Block = 512 thr (8 waves), one output row x
// 256 oc; wave tile = 32 oc x 112 pix (acc 56 AGPR + 64 VGPR fits the 128-reg
// unified budget) -> 2 blocks/CU = 4 waves/SIMD. K = 4 quarters of 32 ch;
// TRIPLE-buffered LDS (65.3 KB), stage(q+2) at quarter start (barrier drains
// only ~9-tap-old loads); distance-1 A-prefetch in a 2-deep parity ring.
// [R16: verified-best configuration (R9), reverted after R10-R15 restructures
//  (tap rotation, B-reg ring, 64-oc pixel-split x3) all measured worse.]
__global__ __launch_bounds__(512, 4) void conv_mfma_kernel(const ushort* __restrict__ xn,
                                                           const ushort* __restrict__ wp,
                                                           const float* __restrict__ bias,
                                                           float* __restrict__ out) {
  __shared__ ushort lds[3 * 340 * 32];  // 3 quarter buffers, 21.75 KB each = 65280 B
  const int bid = blockIdx.x;
  // bijective XCD swizzle (3520 = 8*440): consecutive oh share an XCD's L2
  const int orig = (bid & 7) * 440 + (bid >> 3);
  const int n = orig / HO;
  const int oh = orig - n * HO;
  const int t = threadIdx.x;
  const int lane = t & 63;
  const int wid = t >> 6;  // 0..7: oc 32-block
  const int lane15 = lane & 15;
  const int laneh = lane >> 4;  // 0..3
  const int oc0 = wid * 32;
  char* ldsb = (char*)lds;

  f32x4 acc[2][7] = {};  // [mf: oc 16-frag][nf: ow 16-frag] — 56 regs
  s16x8 abuf[2][2];      // A parity ring (16 regs)

#define A_PREFETCH(gg)                                                                   \
  {                                                                                      \
    const int q_ = (gg) / 9, kk_ = (gg) - q_ * 9;                                        \
    const ushort* wb_ = wp + ((size_t)(kk_ * 4 + q_)) * 8192 + (oc0 + lane15) * 32 +     \
                        laneh * 8;                                                       \
    _Pragma("unroll") for (int mf = 0; mf < 2; ++mf)                                     \
        abuf[(gg) & 1][mf] = *(const s16x8*)(wb_ + mf * 512);                            \
  }

#define STAGE(qq)                                                                        \
  {                                                                                      \
    const char* gsb_ =                                                                   \
        (const char*)(xn + ((((size_t)n * 4 + (qq)) * HI + oh) * WI) * 32);              \
    char* ldst_ = ldsb + (((qq) % 3) * 21760);                                           \
    _Pragma("unroll") for (int i = 0; i < 3; ++i) {                                      \
      int idx = i * 512 + t;                                                             \
      if (idx < 1344) {                                                                  \
        int L = idx * 16;                                                                \
        int go = L ^ (((L >> 7) & 3) << 4);                                              \
        __builtin_amdgcn_global_load_lds((gu32*)(gsb_ + go), (lu32*)(ldst_ + L), 16, 0,  \
                                         0);                                             \
      }                                                                                  \
    }                                                                                    \
  }

  // ---- prologue: A(0), A(1) first (clean waits), then stage(0), stage(1) ----
  A_PREFETCH(0)
  A_PREFETCH(1)
  STAGE(0)
  STAGE(1)
  __syncthreads();  // drains prologue (once per block)

  #pragma unroll
  for (int q = 0; q < 4; ++q) {
    if (q) __syncthreads();  // in-flight loads here are ~9 steps old: free drain
    if (q < 2) STAGE(q + 2)  // triple-buffer: 2-quarter lead time
    const int qb = (q % 3) * 21760;
    #pragma unroll
    for (int kk = 0; kk < 9; ++kk) {
      const int g = q * 9 + kk;
      const int kh = kk / 3, kw = kk - kh * 3;
      if (g + 1 < 36) A_PREFETCH(g + 1)
      // B fragments in two groups (4 then 3) to cap register live-range
      __builtin_amdgcn_s_setprio(1);
      {
        s16x8 b0[4];
        #pragma unroll
        for (int nf = 0; nf < 4; ++nf) {
          int R = kh * WI + nf * 16 + lane15 + kw;
          int addr = qb + (R << 6) + ((laneh ^ ((R >> 1) & 3)) << 4);
          b0[nf] = *(const s16x8*)(ldsb + addr);
        }
        #pragma unroll
        for (int nf = 0; nf < 4; ++nf)
          #pragma unroll
          for (int mf = 0; mf < 2; ++mf)
            acc[mf][nf] = __builtin_amdgcn_mfma_f32_16x16x32_bf16(abuf[g & 1][mf], b0[nf],
                                                                  acc[mf][nf], 0, 0, 0);
      }
      {
        s16x8 b1[3];
        #pragma unroll
        for (int nf = 0; nf < 3; ++nf) {
          int R = kh * WI + (nf + 4) * 16 + lane15 + kw;
          int addr = qb + (R << 6) + ((laneh ^ ((R >> 1) & 3)) << 4);
          b1[nf] = *(const s16x8*)(ldsb + addr);
        }
        #pragma unroll
        for (int nf = 0; nf < 3; ++nf)
          #pragma unroll
          for (int mf = 0; mf < 2; ++mf)
            acc[mf][nf + 4] = __builtin_amdgcn_mfma_f32_16x16x32_bf16(
                abuf[g & 1][mf], b1[nf], acc[mf][nf + 4], 0, 0, 0);
      }
      __builtin_amdgcn_s_setprio(0);
    }
  }
#undef A_PREFETCH
#undef STAGE

  // ---- epilogue: D col=lane15 -> ow, row=laneh*4+r -> oc ----
  float* outb = out + ((size_t)n * OC) * (HO * WO) + (size_t)oh * WO;
  #pragma unroll
  for (int mf = 0; mf < 2; ++mf) {
    #pragma unroll
    for (int r = 0; r < 4; ++r) {
      const int oc = oc0 + mf * 16 + laneh * 4 + r;
      const float bv = bias[oc];
      float* op = outb + (size_t)oc * (HO * WO);
      #pragma unroll
      for (int nf = 0; nf < 7; ++nf) {
        int ow = nf * 16 + lane15;
        if (ow < WO) op[ow] = acc[mf][nf][r] + bv;
      }
    }
  }
}

// Correctness fallback if ws is too small for the packed bf16 buffers.
__global__ __launch_bounds__(256) void conv_naive_kernel(const float* __restrict__ x,
                                                         const float* __restrict__ w,
                                                         const float* __restrict__ bias,
                                                         float* __restrict__ out) {
  long i = (long)blockIdx.x * 256 + threadIdx.x;
  const long total = (long)NI * OC * HO * WO;
  if (i >= total) return;
  int ow = (int)(i % WO);
  long r1 = i / WO;
  int oh = (int)(r1 % HO);
  long r2 = r1 / HO;
  int oc = (int)(r2 % OC);
  int n = (int)(r2 / OC);
  float s = bias[oc];
  const float* xb = x + ((size_t)n * CI * HI) * WI;
  const float* wb = w + (size_t)oc * CI * 9;
  for (int c = 0; c < CI; ++c)
    for (int kh = 0; kh < 3; ++kh)
      for (int kw = 0; kw < 3; ++kw)
        s += xb[((size_t)c * HI + oh + kh) * WI + ow + kw] * wb[(c * 3 + kh) * 3 + kw];
  out[i] = s;
}

extern "C" void kernel_launch(void* const* d_in, const int* in_sizes, int n_in,
                              void* d_out, int out_size, void* d_ws, size_t ws_size,
                              hipStream_t stream) {
  const float* x = (const float*)d_in[0];
  const float* w = (const float*)d_in[1];
  const float* bias = (const float*)d_in[2];
  float* out = (float*)d_out;

  const size_t xn_elems = (size_t)NI * 4 * HI * WI * 32;  // 51,380,224
  const size_t wp_elems = (size_t)9 * 4 * 256 * 32;       // 294,912
  const size_t need = (xn_elems + wp_elems) * sizeof(ushort);

  if (ws_size >= need) {
    ushort* xnw = (ushort*)d_ws;
    ushort* wpw = xnw + xn_elems;
    hipLaunchKernelGGL(pack_w_kernel, dim3((unsigned)(wp_elems / 256)), dim3(256), 0, stream,
                       w, wpw);
    hipLaunchKernelGGL(to_nhwc_kernel, dim3(NI * HI), dim3(256), 0, stream, x, xnw);
    hipLaunchKernelGGL(conv_mfma_kernel, dim3(NI * HO), dim3(512), 0, stream, xnw, wpw, bias,
                       out);
  } else {
    long total = (long)NI * OC * HO * WO;
    hipLaunchKernelGGL(conv_naive_kernel, dim3((unsigned)((total + 255) / 256)), dim3(256), 0,
                       stream, x, w, bias, out);
  }
}